// Round 1
// 1004.238 us; speedup vs baseline: 1.0103x; 1.0103x over previous
//
#include <hip/hip_runtime.h>

#define B_ 8
#define H_ 8
#define N_ 4096
#define K_ 32
#define D_ 16
#define ROWS_ 16          // rows (n values) per wave
#define NBLK_ 4096        // 4096 blocks * 4 waves * 16 rows = 262144 rows

__device__ __forceinline__ float4 ld4(const float* p) {
    return *reinterpret_cast<const float4*>(p);
}

// one row's streamed data, kept in registers while the next row prefetches
struct RowRegs {
    float4 k1, k2, v1, v2;   // k/v: the HBM stream (4 KB per row per wave)
    float4 f0, f1, f2;       // xyz for the energy term (L2-resident)
    float qa, qb;            // raw q values (scale applied later — keeps
                             // the prefetch free of load-dependent VALU)
};

__global__ __launch_bounds__(256) void pe_attn_kernel(
    const float* __restrict__ q, const float* __restrict__ kmat,
    const float* __restrict__ vmat, const float* __restrict__ xyz,
    const float* __restrict__ W1, const float* __restrict__ b1,
    const float* __restrict__ W2, const float* __restrict__ b2,
    float* __restrict__ out)
{
    const int lane = threadIdx.x & 63;
    const int wid  = threadIdx.x >> 6;

    // wave -> (b,h) fixed, 16 consecutive n.  bh in low bits: all 8 h of a
    // (b, n-range) run concurrently chip-wide -> xyz stays hot in cache.
    const int bh = blockIdx.x & 63;                          // b*H + h
    const int h  = bh & (H_ - 1);
    const int b  = bh >> 3;
    const int n0 = (((blockIdx.x >> 6) << 2) | wid) << 4;    // first n

    const int dg = lane >> 3;       // d-group (energy phase)
    const int kg = lane & 7;        // column group: cols 4*kg..4*kg+3
    const int kq = lane >> 2;       // 0..15 (output phase)
    const int d0 = (lane & 3) << 2;
    const int khi = kq >> 3;

    __shared__ float attn_s[4][2][32];   // per-wave, double-phased (A/B)

    // ---- loop-invariant loads (hoisted: were re-fetched every row) ----
    const float w10 = W1[h] * 0.25f, w11 = W1[H_ + h] * 0.25f, w12 = W1[2 * H_ + h] * 0.25f;
    const float bb1 = b1[h] * 0.25f;
    const int o1 = ((kq & 7) << 4) | d0;
    const float4 w20 = ld4(W2 + o1);
    const float4 w21 = ld4(W2 + 128 + o1);
    const float4 w22 = ld4(W2 + 256 + o1);
    const float4 bb2 = ld4(b2 + o1);

    const size_t rowbase = (size_t)bh * N_ + n0;
    const float* kp = kmat + rowbase * (D_ * K_);
    const float* vp = vmat + rowbase * (D_ * K_);
    const float* qp = q + rowbase * D_;
    const float* xp = xyz + (size_t)(b * N_ + n0) * (K_ * 3) + 12 * kg;
    const float* xvb = xyz + (size_t)b * N_ * (K_ * 3);
    float* op = out + ((size_t)(b * N_ + n0) * H_ + h) * D_ + d0;

    // pure loads, no dependent arithmetic -> no implicit waitcnt here
    auto pref = [&](const float* kr, const float* vr, const float* qr,
                    const float* xr) {
        RowRegs r;
        r.k1 = ld4(kr + 4 * lane);
        r.k2 = ld4(kr + 256 + 4 * lane);
        r.v1 = ld4(vr + 4 * lane);
        r.v2 = ld4(vr + 256 + 4 * lane);
        r.qa = qr[dg];
        r.qb = qr[8 + dg];
        r.f0 = ld4(xr);
        r.f1 = ld4(xr + 4);
        r.f2 = ld4(xr + 8);
        return r;
    };

    // per-row math: verbatim the harness-verified arithmetic
    auto compute = [&](const RowRegs& r, int n, float* asrow, float* opn) {
        // v_xyz scatter sources issued first so their (L2) latency hides
        // under the energy shuffle chain
        const int nsrc = (h << 9) | (n >> 3);
        const int ks1 = ((n & 7) << 2) + khi;
        const float* xv = xvb + (size_t)nsrc * (K_ * 3) + ks1 * 3;
        const float X1 = xv[0], Y1 = xv[1], Z1 = xv[2];
        const float X2 = xv[6], Y2 = xv[7], Z2 = xv[8];   // ks2 = ks1+2

        const float qa = r.qa * 0.25f;    // fold 1/sqrt(D)=0.25 into q
        const float qb = r.qb * 0.25f;

        // energy = (q.k)/4
        float4 e;
        e.x = fmaf(qa, r.k1.x, qb * r.k2.x);
        e.y = fmaf(qa, r.k1.y, qb * r.k2.y);
        e.z = fmaf(qa, r.k1.z, qb * r.k2.z);
        e.w = fmaf(qa, r.k1.w, qb * r.k2.w);
        #pragma unroll
        for (int m = 8; m <= 32; m <<= 1) {   // reduce over 8 d-groups
            e.x += __shfl_xor(e.x, m);
            e.y += __shfl_xor(e.y, m);
            e.z += __shfl_xor(e.z, m);
            e.w += __shfl_xor(e.w, m);
        }
        // + e_xyz/4 (scale pre-folded into w1*/bb1)
        e.x += fmaf(r.f0.x, w10, fmaf(r.f0.y, w11, fmaf(r.f0.z, w12, bb1)));
        e.y += fmaf(r.f0.w, w10, fmaf(r.f1.x, w11, fmaf(r.f1.y, w12, bb1)));
        e.z += fmaf(r.f1.z, w10, fmaf(r.f1.w, w11, fmaf(r.f2.x, w12, bb1)));
        e.w += fmaf(r.f2.y, w10, fmaf(r.f2.z, w11, fmaf(r.f2.w, w12, bb1)));

        // softmax over 32 columns
        float mx = fmaxf(fmaxf(e.x, e.y), fmaxf(e.z, e.w));
        #pragma unroll
        for (int m = 1; m <= 4; m <<= 1) mx = fmaxf(mx, __shfl_xor(mx, m));

        float4 p;
        p.x = __expf(e.x - mx);
        p.y = __expf(e.y - mx);
        p.z = __expf(e.z - mx);
        p.w = __expf(e.w - mx);
        float s = (p.x + p.y) + (p.z + p.w);
        #pragma unroll
        for (int m = 1; m <= 4; m <<= 1) s += __shfl_xor(s, m);
        float invs = 1.0f / s;

        // wave-local LDS broadcast (phase-split buffer, no __syncthreads)
        if (lane < 8) {
            float4 a4 = make_float4(p.x * invs, p.y * invs, p.z * invs, p.w * invs);
            *reinterpret_cast<float4*>(asrow + 4 * kg) = a4;
        }
        __builtin_amdgcn_wave_barrier();
        float a1 = asrow[kq];
        float a2 = asrow[16 + kq];
        __builtin_amdgcn_wave_barrier();

        // output: sum_k attn[k] * (v[k,d] + v_xyz[k,d])
        float4 acc;
        float vx;
        vx = fmaf(X1, w20.x, fmaf(Y1, w21.x, fmaf(Z1, w22.x, bb2.x)));
        acc.x = a1 * (r.v1.x + vx);
        vx = fmaf(X1, w20.y, fmaf(Y1, w21.y, fmaf(Z1, w22.y, bb2.y)));
        acc.y = a1 * (r.v1.y + vx);
        vx = fmaf(X1, w20.z, fmaf(Y1, w21.z, fmaf(Z1, w22.z, bb2.z)));
        acc.z = a1 * (r.v1.z + vx);
        vx = fmaf(X1, w20.w, fmaf(Y1, w21.w, fmaf(Z1, w22.w, bb2.w)));
        acc.w = a1 * (r.v1.w + vx);

        vx = fmaf(X2, w20.x, fmaf(Y2, w21.x, fmaf(Z2, w22.x, bb2.x)));
        acc.x = fmaf(a2, r.v2.x + vx, acc.x);
        vx = fmaf(X2, w20.y, fmaf(Y2, w21.y, fmaf(Z2, w22.y, bb2.y)));
        acc.y = fmaf(a2, r.v2.y + vx, acc.y);
        vx = fmaf(X2, w20.z, fmaf(Y2, w21.z, fmaf(Z2, w22.z, bb2.z)));
        acc.z = fmaf(a2, r.v2.z + vx, acc.z);
        vx = fmaf(X2, w20.w, fmaf(Y2, w21.w, fmaf(Z2, w22.w, bb2.w)));
        acc.w = fmaf(a2, r.v2.w + vx, acc.w);

        #pragma unroll
        for (int m = 4; m <= 32; m <<= 1) {   // reduce over k (lane bits 2..5)
            acc.x += __shfl_xor(acc.x, m);
            acc.y += __shfl_xor(acc.y, m);
            acc.z += __shfl_xor(acc.z, m);
            acc.w += __shfl_xor(acc.w, m);
        }
        if (lane < 4) *reinterpret_cast<float4*>(opn) = acc;
    };

    // ---- software-pipelined main loop: compute row i while rows i+1/i+2
    //      stream from HBM (A/B register double-buffer, all-static names) ----
    RowRegs A = pref(kp, vp, qp, xp);
    #pragma unroll 1
    for (int i = 0; i < ROWS_; i += 2) {
        RowRegs Bv = pref(kp + 512, vp + 512, qp + 16, xp + 96);
        compute(A, n0 + i, &attn_s[wid][0][0], op);
        if (i + 2 < ROWS_)                 // wave-uniform guard (no OOB row)
            A = pref(kp + 1024, vp + 1024, qp + 32, xp + 192);
        compute(Bv, n0 + i + 1, &attn_s[wid][1][0], op + 128);
        kp += 1024; vp += 1024; qp += 32; xp += 192; op += 256;
    }
}

extern "C" void kernel_launch(void* const* d_in, const int* in_sizes, int n_in,
                              void* d_out, int out_size, void* d_ws, size_t ws_size,
                              hipStream_t stream) {
    const float* q   = (const float*)d_in[0];
    const float* k   = (const float*)d_in[1];
    const float* v   = (const float*)d_in[2];
    const float* xyz = (const float*)d_in[3];
    const float* W1  = (const float*)d_in[4];
    const float* b1  = (const float*)d_in[5];
    const float* W2  = (const float*)d_in[6];
    const float* b2  = (const float*)d_in[7];
    float* out = (float*)d_out;

    dim3 grid(NBLK_);      // 4 waves/block, 16 rows/wave, (b,h) fixed per wave
    dim3 block(256);
    hipLaunchKernelGGL(pe_attn_kernel, grid, block, 0, stream,
                       q, k, v, xyz, W1, b1, W2, b2, out);
}